// Round 4
// baseline (170.894 us; speedup 1.0000x reference)
//
#include <hip/hip_runtime.h>

using f16   = _Float16;
using f16x4 = __attribute__((ext_vector_type(4))) _Float16;
using f16x8 = __attribute__((ext_vector_type(8))) _Float16;
using f32x4 = __attribute__((ext_vector_type(4))) float;

#define BDIM 4
#define EDIM 512
#define LDIM 512
#define VDIM 32000
#define RDIM 2048            // B*L
#define INV_TAU 0.1f

using gcvoid = const __attribute__((address_space(1))) void;
using lvoid  = __attribute__((address_space(3))) void;

__device__ __forceinline__ void gload_lds16(const void* g, void* l) {
  __builtin_amdgcn_global_load_lds((gcvoid*)g, (lvoid*)l, 16, 0, 0);
}

// ---------------- kernel 1: DE [B,E,L] f32 -> A16 [R=B*L][E] f16 (transpose+convert)
__global__ void cvtA_kernel(const float* __restrict__ DE, f16* __restrict__ A16) {
  __shared__ float tile[64][65];
  const int b  = blockIdx.z;
  const int e0 = blockIdx.y * 64;
  const int l0 = blockIdx.x * 64;
  const int t  = threadIdx.x;
#pragma unroll
  for (int i = 0; i < 4; ++i) {
    int idx = t + i * 256;
    int el  = idx >> 4;
    int l4  = (idx & 15) * 4;
    float4 v = *reinterpret_cast<const float4*>(
        DE + (size_t)(b * 512 + e0 + el) * 512 + l0 + l4);
    tile[el][l4 + 0] = v.x;
    tile[el][l4 + 1] = v.y;
    tile[el][l4 + 2] = v.z;
    tile[el][l4 + 3] = v.w;
  }
  __syncthreads();
#pragma unroll
  for (int i = 0; i < 4; ++i) {
    int idx = t + i * 256;
    int ll  = idx >> 4;
    int e4  = (idx & 15) * 4;
    f16x4 h;
    h[0] = (f16)tile[e4 + 0][ll];
    h[1] = (f16)tile[e4 + 1][ll];
    h[2] = (f16)tile[e4 + 2][ll];
    h[3] = (f16)tile[e4 + 3][ll];
    *reinterpret_cast<f16x4*>(A16 + (size_t)(b * 512 + l0 + ll) * 512 + e0 + e4) = h;
  }
}

// ---------------- kernel 2: M [V,E] f32 -> B16 [V][E] f16 (stream convert)
__global__ void cvtM_kernel(const float* __restrict__ M, f16* __restrict__ B16) {
  const size_t N4 = (size_t)VDIM * EDIM / 4;
  const size_t stride = (size_t)gridDim.x * blockDim.x;
  for (size_t i = (size_t)blockIdx.x * blockDim.x + threadIdx.x; i < N4; i += stride) {
    float4 v = reinterpret_cast<const float4*>(M)[i];
    f16x4 h = { (f16)v.x, (f16)v.y, (f16)v.z, (f16)v.w };
    reinterpret_cast<f16x4*>(B16)[i] = h;
  }
}

// ---------------- kernel 3: fused GEMM + exp + vocab-sum
// Block 256x256, 8 waves (2x4), wave tile 128x64, BK=32, 16 K-tiles,
// ring-3 LDS (3 x 32KB = 96KB), counted-vmcnt pipeline (stage t+2 during t,
// boundary s_waitcnt vmcnt(4) lgkmcnt(0) + s_barrier; never drain early).
// Granule swizzle both sides (rule #21, 0-conflict-verified in R3):
// LDS granule g of row r holds global k-chunk g ^ ((r>>1)&3).
__global__ __launch_bounds__(512, 2) void gemm_kernel(const f16* __restrict__ A16,
                                                      const f16* __restrict__ B16,
                                                      float* __restrict__ down) {
  __shared__ __align__(16) char sm[3][32768];   // per buf: A[256][32] | B[256][32] f16
  const int orig = blockIdx.x;                  // 1000 = 8 * 125
  const int rt   = orig & 7;                    // XCD id == row tile: A-stripe L2-resident
  const int ct   = orig >> 3;                   // 0..124
  const int r0   = rt * 256, c0 = ct * 256;
  const int tid  = threadIdx.x;
  const int lane = tid & 63;
  const int w    = tid >> 6;                    // 0..7
  const int wr   = w >> 2, wc = w & 3;          // 2 x 4 wave grid

  // staging: lane l of instr covers LDS bytes instr*1024 + l*16
  //   row = instr*16 + (l>>2); source k-granule = (l&3) ^ ((l>>3)&3)
  const int srow = lane >> 2;
  const int sel  = ((lane & 3) ^ ((lane >> 3) & 3)) * 8;   // f16 elems

  auto stage = [&](int buf, int t) {
    const int kbase = t * 32;
#pragma unroll
    for (int i = 0; i < 2; ++i) {
      int ia = w * 2 + i;                       // 16 instrs cover A rows 0..255
      gload_lds16(A16 + (size_t)(r0 + ia * 16 + srow) * 512 + kbase + sel,
                  &sm[buf][ia * 1024]);
    }
#pragma unroll
    for (int i = 0; i < 2; ++i) {
      int ib = w * 2 + i;                       // 16 instrs cover B rows 0..255
      gload_lds16(B16 + (size_t)(c0 + ib * 16 + srow) * 512 + kbase + sel,
                  &sm[buf][16384 + ib * 1024]);
    }
  };

  f32x4 acc[8][4] = {};

  // prologue: stage K0,K1 (8 loads/wave in flight), wait oldest 4 (K0)
  stage(0, 0);
  stage(1, 1);
  asm volatile("s_waitcnt vmcnt(4)" ::: "memory");
  __builtin_amdgcn_s_barrier();
  asm volatile("" ::: "memory");

  // swizzled read granule: kc = lane>>4, row bits 1-2 = (lane>>1)&3
  const int koff = ((lane >> 4) ^ ((lane >> 1) & 3)) * 16;
  const int arow = (wr * 128 + (lane & 15)) * 64;           // + mi*1024
  const int brow = 16384 + (wc * 64 + (lane & 15)) * 64;    // + ni*1024

#pragma unroll
  for (int t = 0; t < 16; ++t) {
    const int cur = t % 3;
    f16x8 af[8], bf[4];
#pragma unroll
    for (int mi = 0; mi < 8; ++mi)
      af[mi] = *reinterpret_cast<const f16x8*>(&sm[cur][arow + mi * 1024 + koff]);
#pragma unroll
    for (int ni = 0; ni < 4; ++ni)
      bf[ni] = *reinterpret_cast<const f16x8*>(&sm[cur][brow + ni * 1024 + koff]);

    if (t + 2 < 16) stage((t + 2) % 3, t + 2);

    __builtin_amdgcn_s_setprio(1);
#pragma unroll
    for (int mi = 0; mi < 8; ++mi)
#pragma unroll
      for (int ni = 0; ni < 4; ++ni)
        acc[mi][ni] = __builtin_amdgcn_mfma_f32_16x16x32_f16(
            af[mi], bf[ni], acc[mi][ni], 0, 0, 0);
    __builtin_amdgcn_s_setprio(0);

    if (t < 15) {
      // in flight: K(t+1) 4 + K(t+2) 4. Need K(t+1) -> vmcnt(4).
      // lgkmcnt(0) closes the ring-slot WAR (buf (t+2)%3 == buf (t-1)%3).
      if (t <= 13) asm volatile("s_waitcnt vmcnt(4) lgkmcnt(0)" ::: "memory");
      else         asm volatile("s_waitcnt vmcnt(0) lgkmcnt(0)" ::: "memory");
      __builtin_amdgcn_s_barrier();
      asm volatile("" ::: "memory");
    }
  }

  // epilogue: exp + sum over this wave's 64 columns, then atomic into down[]
  // D layout: col = lane&15, row = (lane>>4)*4 + j  (m89-verified)
  const int rbase = r0 + wr * 128;
#pragma unroll
  for (int mi = 0; mi < 8; ++mi) {
    float s0 = 0.f, s1 = 0.f, s2 = 0.f, s3 = 0.f;
#pragma unroll
    for (int ni = 0; ni < 4; ++ni) {
      f32x4 v = acc[mi][ni];
      s0 += __expf(INV_TAU * v[0]);
      s1 += __expf(INV_TAU * v[1]);
      s2 += __expf(INV_TAU * v[2]);
      s3 += __expf(INV_TAU * v[3]);
    }
#pragma unroll
    for (int m = 1; m <= 8; m <<= 1) {
      s0 += __shfl_xor(s0, m);
      s1 += __shfl_xor(s1, m);
      s2 += __shfl_xor(s2, m);
      s3 += __shfl_xor(s3, m);
    }
    if ((lane & 15) == 0) {
      int row = rbase + mi * 16 + (lane >> 4) * 4;
      atomicAdd(&down[row + 0], s0);
      atomicAdd(&down[row + 1], s1);
      atomicAdd(&down[row + 2], s2);
      atomicAdd(&down[row + 3], s3);
    }
  }
}

// ---------------- kernel 4: up = exp(EN.DE/tau); out += up/down  (fp32 exact)
__global__ void finalize_kernel(const float* __restrict__ EN, const float* __restrict__ DE,
                                const float* __restrict__ down, float* __restrict__ out) {
  __shared__ float red[4][64];
  const int r0 = blockIdx.x * 64;
  const int b  = r0 >> 9;
  const int l0 = r0 & 511;
  const int t  = threadIdx.x;
  const int ll = t & 63;
  const int g  = t >> 6;
  float p = 0.f;
  const int ebase = g * 128;
#pragma unroll 4
  for (int e = 0; e < 128; ++e) {
    size_t idx = (size_t)(b * 512 + ebase + e) * 512 + l0 + ll;
    p += EN[idx] * DE[idx];
  }
  red[g][ll] = p;
  __syncthreads();
  if (t < 64) {
    float s = red[0][t] + red[1][t] + red[2][t] + red[3][t];
    float val = __expf(INV_TAU * s) / down[r0 + t];
#pragma unroll
    for (int m = 1; m <= 32; m <<= 1) val += __shfl_xor(val, m);
    if (t == 0) atomicAdd(out, val);
  }
}

extern "C" void kernel_launch(void* const* d_in, const int* in_sizes, int n_in,
                              void* d_out, int out_size, void* d_ws, size_t ws_size,
                              hipStream_t stream) {
  const float* EN = (const float*)d_in[0];
  const float* DE = (const float*)d_in[1];
  const float* M  = (const float*)d_in[2];

  // ws layout: down[2048] f32 | A16 [2048*512] f16 | B16 [32000*512] f16
  float* down = (float*)d_ws;
  f16* A16 = (f16*)((char*)d_ws + 8192);
  f16* B16 = (f16*)((char*)d_ws + 8192 + (size_t)RDIM * EDIM * 2);
  const size_t need = 8192 + (size_t)RDIM * EDIM * 2 + (size_t)VDIM * EDIM * 2;

  hipMemsetAsync(d_out, 0, sizeof(float), stream);
  if (ws_size < need) return;
  hipMemsetAsync(d_ws, 0, RDIM * sizeof(float), stream);

  cvtA_kernel<<<dim3(8, 8, 4), 256, 0, stream>>>(DE, A16);
  cvtM_kernel<<<2048, 256, 0, stream>>>(M, B16);
  gemm_kernel<<<1000, 512, 0, stream>>>(A16, B16, down);
  finalize_kernel<<<32, 256, 0, stream>>>(EN, DE, down, (float*)d_out);
}

// Round 5
// 125.456 us; speedup vs baseline: 1.3622x; 1.3622x over previous
//
#include <hip/hip_runtime.h>

using f16   = _Float16;
using f16x4 = __attribute__((ext_vector_type(4))) _Float16;
using f16x8 = __attribute__((ext_vector_type(8))) _Float16;
using f32x4 = __attribute__((ext_vector_type(4))) float;

#define BDIM 4
#define EDIM 512
#define LDIM 512
#define VDIM 32000
#define RDIM 2048            // B*L
#define INV_TAU 0.1f

using gcvoid = const __attribute__((address_space(1))) void;
using lvoid  = __attribute__((address_space(3))) void;

__device__ __forceinline__ void gload_lds16(const void* g, void* l) {
  __builtin_amdgcn_global_load_lds((gcvoid*)g, (lvoid*)l, 16, 0, 0);
}

// ---------------- kernel 1: DE [B,E,L] f32 -> A16 [R=B*L][E] f16 (transpose+convert)
__global__ void cvtA_kernel(const float* __restrict__ DE, f16* __restrict__ A16) {
  __shared__ float tile[64][65];
  const int b  = blockIdx.z;
  const int e0 = blockIdx.y * 64;
  const int l0 = blockIdx.x * 64;
  const int t  = threadIdx.x;
#pragma unroll
  for (int i = 0; i < 4; ++i) {
    int idx = t + i * 256;
    int el  = idx >> 4;
    int l4  = (idx & 15) * 4;
    float4 v = *reinterpret_cast<const float4*>(
        DE + (size_t)(b * 512 + e0 + el) * 512 + l0 + l4);
    tile[el][l4 + 0] = v.x;
    tile[el][l4 + 1] = v.y;
    tile[el][l4 + 2] = v.z;
    tile[el][l4 + 3] = v.w;
  }
  __syncthreads();
#pragma unroll
  for (int i = 0; i < 4; ++i) {
    int idx = t + i * 256;
    int ll  = idx >> 4;
    int e4  = (idx & 15) * 4;
    f16x4 h;
    h[0] = (f16)tile[e4 + 0][ll];
    h[1] = (f16)tile[e4 + 1][ll];
    h[2] = (f16)tile[e4 + 2][ll];
    h[3] = (f16)tile[e4 + 3][ll];
    *reinterpret_cast<f16x4*>(A16 + (size_t)(b * 512 + l0 + ll) * 512 + e0 + e4) = h;
  }
}

// ---------------- kernel 2: M [V,E] f32 -> B16 [V][E] f16 (stream convert)
__global__ void cvtM_kernel(const float* __restrict__ M, f16* __restrict__ B16) {
  const size_t N4 = (size_t)VDIM * EDIM / 4;
  const size_t stride = (size_t)gridDim.x * blockDim.x;
  for (size_t i = (size_t)blockIdx.x * blockDim.x + threadIdx.x; i < N4; i += stride) {
    float4 v = reinterpret_cast<const float4*>(M)[i];
    f16x4 h = { (f16)v.x, (f16)v.y, (f16)v.z, (f16)v.w };
    reinterpret_cast<f16x4*>(B16)[i] = h;
  }
}

// ---------------- kernel 3: fused GEMM + exp + vocab-sum
// Block 256x128, 4 waves (2x2), wave tile 128x64, BK=32, 16 K-tiles,
// ring-3 LDS (3 x 24KB = 72KB -> 2 blocks/CU), counted-vmcnt pipeline:
// stage K(t+2) during t (6 loads/wave), boundary s_waitcnt vmcnt(6) lgkmcnt(0)
// + s_barrier (never drain early). Granule swizzle both sides (rule #21,
// 0-conflict verified R3/R4): LDS granule g of row r holds k-chunk g^((r>>1)&3).
// XCD mapping (m204 bijective, 2000=8*250): each XCD gets ~31 contiguous B
// panels x all 8 row tiles -> B panel L2-hot (reused 8x), A16 2MB L2-resident.
__global__ __launch_bounds__(256, 2) void gemm_kernel(const f16* __restrict__ A16,
                                                      const f16* __restrict__ B16,
                                                      float* __restrict__ down) {
  __shared__ __align__(16) char sm[3][24576];   // per buf: A[256][32] | B[128][32] f16
  const int orig = blockIdx.x;                  // 2000 = 8 * 250
  const int wgid = (orig & 7) * 250 + (orig >> 3);
  const int rt   = wgid & 7;                    // 8 row tiles of 256
  const int ct   = wgid >> 3;                   // 250 col tiles of 128
  const int r0   = rt * 256, c0 = ct * 128;
  const int tid  = threadIdx.x;
  const int lane = tid & 63;
  const int w    = tid >> 6;                    // 0..3
  const int wr   = w >> 1, wc = w & 1;          // 2 x 2 wave grid

  // staging: lane l of instr covers LDS bytes instr*1024 + l*16
  //   row = instr*16 + (l>>2); source k-granule = (l&3) ^ ((l>>3)&3)
  const int srow = lane >> 2;
  const int sel  = ((lane & 3) ^ ((lane >> 3) & 3)) * 8;   // f16 elems

  auto stage = [&](int buf, int t) {
    const int kbase = t * 32;
#pragma unroll
    for (int i = 0; i < 4; ++i) {
      int ia = w * 4 + i;                       // 16 instrs cover A rows 0..255
      gload_lds16(A16 + (size_t)(r0 + ia * 16 + srow) * 512 + kbase + sel,
                  &sm[buf][ia * 1024]);
    }
#pragma unroll
    for (int i = 0; i < 2; ++i) {
      int ib = w * 2 + i;                       // 8 instrs cover B rows 0..127
      gload_lds16(B16 + (size_t)(c0 + ib * 16 + srow) * 512 + kbase + sel,
                  &sm[buf][16384 + ib * 1024]);
    }
  };

  f32x4 acc[8][4] = {};

  // prologue: stage K0,K1 (12 loads/wave in flight), wait oldest 6 (K0)
  stage(0, 0);
  stage(1, 1);
  asm volatile("s_waitcnt vmcnt(6)" ::: "memory");
  __builtin_amdgcn_s_barrier();
  asm volatile("" ::: "memory");

  // swizzled read granule: kc = lane>>4, row bits 1-2 = (lane>>1)&3
  const int koff = ((lane >> 4) ^ ((lane >> 1) & 3)) * 16;
  const int arow = (wr * 128 + (lane & 15)) * 64;           // + mi*1024
  const int brow = 16384 + (wc * 64 + (lane & 15)) * 64;    // + ni*1024

#pragma unroll
  for (int t = 0; t < 16; ++t) {
    const int cur = t % 3;
    f16x8 af[8], bf[4];
#pragma unroll
    for (int mi = 0; mi < 8; ++mi)
      af[mi] = *reinterpret_cast<const f16x8*>(&sm[cur][arow + mi * 1024 + koff]);
#pragma unroll
    for (int ni = 0; ni < 4; ++ni)
      bf[ni] = *reinterpret_cast<const f16x8*>(&sm[cur][brow + ni * 1024 + koff]);

    if (t + 2 < 16) stage((t + 2) % 3, t + 2);

    __builtin_amdgcn_s_setprio(1);
#pragma unroll
    for (int mi = 0; mi < 8; ++mi)
#pragma unroll
      for (int ni = 0; ni < 4; ++ni)
        acc[mi][ni] = __builtin_amdgcn_mfma_f32_16x16x32_f16(
            af[mi], bf[ni], acc[mi][ni], 0, 0, 0);
    __builtin_amdgcn_s_setprio(0);

    if (t < 15) {
      // in flight: K(t+1) 6 + K(t+2) 6. Need K(t+1) -> vmcnt(6).
      // lgkmcnt(0) closes the ring-slot WAR (buf (t+2)%3 == buf (t-1)%3).
      if (t <= 13) asm volatile("s_waitcnt vmcnt(6) lgkmcnt(0)" ::: "memory");
      else         asm volatile("s_waitcnt vmcnt(0) lgkmcnt(0)" ::: "memory");
      __builtin_amdgcn_s_barrier();
      asm volatile("" ::: "memory");
    }
  }

  // epilogue: exp + sum over this wave's 64 columns, then atomic into down[]
  // D layout: col = lane&15, row = (lane>>4)*4 + j  (m89-verified)
  const int rbase = r0 + wr * 128;
#pragma unroll
  for (int mi = 0; mi < 8; ++mi) {
    float s0 = 0.f, s1 = 0.f, s2 = 0.f, s3 = 0.f;
#pragma unroll
    for (int ni = 0; ni < 4; ++ni) {
      f32x4 v = acc[mi][ni];
      s0 += __expf(INV_TAU * v[0]);
      s1 += __expf(INV_TAU * v[1]);
      s2 += __expf(INV_TAU * v[2]);
      s3 += __expf(INV_TAU * v[3]);
    }
#pragma unroll
    for (int m = 1; m <= 8; m <<= 1) {
      s0 += __shfl_xor(s0, m);
      s1 += __shfl_xor(s1, m);
      s2 += __shfl_xor(s2, m);
      s3 += __shfl_xor(s3, m);
    }
    if ((lane & 15) == 0) {
      int row = rbase + mi * 16 + (lane >> 4) * 4;
      atomicAdd(&down[row + 0], s0);
      atomicAdd(&down[row + 1], s1);
      atomicAdd(&down[row + 2], s2);
      atomicAdd(&down[row + 3], s3);
    }
  }
}

// ---------------- kernel 4: up = exp(EN.DE/tau); out += up/down  (fp32 exact)
__global__ void finalize_kernel(const float* __restrict__ EN, const float* __restrict__ DE,
                                const float* __restrict__ down, float* __restrict__ out) {
  __shared__ float red[4][64];
  const int r0 = blockIdx.x * 64;
  const int b  = r0 >> 9;
  const int l0 = r0 & 511;
  const int t  = threadIdx.x;
  const int ll = t & 63;
  const int g  = t >> 6;
  float p = 0.f;
  const int ebase = g * 128;
#pragma unroll 4
  for (int e = 0; e < 128; ++e) {
    size_t idx = (size_t)(b * 512 + ebase + e) * 512 + l0 + ll;
    p += EN[idx] * DE[idx];
  }
  red[g][ll] = p;
  __syncthreads();
  if (t < 64) {
    float s = red[0][t] + red[1][t] + red[2][t] + red[3][t];
    float val = __expf(INV_TAU * s) / down[r0 + t];
#pragma unroll
    for (int m = 1; m <= 32; m <<= 1) val += __shfl_xor(val, m);
    if (t == 0) atomicAdd(out, val);
  }
}

extern "C" void kernel_launch(void* const* d_in, const int* in_sizes, int n_in,
                              void* d_out, int out_size, void* d_ws, size_t ws_size,
                              hipStream_t stream) {
  const float* EN = (const float*)d_in[0];
  const float* DE = (const float*)d_in[1];
  const float* M  = (const float*)d_in[2];

  // ws layout: down[2048] f32 | A16 [2048*512] f16 | B16 [32000*512] f16
  float* down = (float*)d_ws;
  f16* A16 = (f16*)((char*)d_ws + 8192);
  f16* B16 = (f16*)((char*)d_ws + 8192 + (size_t)RDIM * EDIM * 2);
  const size_t need = 8192 + (size_t)RDIM * EDIM * 2 + (size_t)VDIM * EDIM * 2;

  hipMemsetAsync(d_out, 0, sizeof(float), stream);
  if (ws_size < need) return;
  hipMemsetAsync(d_ws, 0, RDIM * sizeof(float), stream);

  cvtA_kernel<<<dim3(8, 8, 4), 256, 0, stream>>>(DE, A16);
  cvtM_kernel<<<2048, 256, 0, stream>>>(M, B16);
  gemm_kernel<<<2000, 256, 0, stream>>>(A16, B16, down);
  finalize_kernel<<<32, 256, 0, stream>>>(EN, DE, down, (float*)d_out);
}